// Round 1
// baseline (152.174 us; speedup 1.0000x reference)
//
#include <hip/hip_runtime.h>

#define NN 8192
#define KK 512
#define INVT 14.285714285714286f  /* 1/0.07 */
#define EPSF 1e-6f

#define BM 128
#define BN 64
#define CSPLIT 8
#define COLS_PER_BLOCK (NN / CSPLIT) /* 1024 */
#define NTILES (COLS_PER_BLOCK / BN) /* 16 */

typedef short bf16x8 __attribute__((ext_vector_type(8)));
typedef float f32x4 __attribute__((ext_vector_type(4)));

__device__ __forceinline__ unsigned short f2bf(float f) {
  unsigned int u = __float_as_uint(f);
  u = u + 0x7FFFu + ((u >> 16) & 1u);
  return (unsigned short)(u >> 16);
}

__device__ __forceinline__ void load_lds16(const void* g, void* l) {
  __builtin_amdgcn_global_load_lds(
      (const __attribute__((address_space(1))) unsigned int*)g,
      (__attribute__((address_space(3))) unsigned int*)l, 16, 0, 0);
}

// Kernel 1: fp32 -> bf16 conversion of features + per-class counts.
__global__ void prep_kernel(const float* __restrict__ feats,
                            const int* __restrict__ labels,
                            unsigned short* __restrict__ fb,
                            int* __restrict__ cnt) {
  int tid = blockIdx.x * 256 + threadIdx.x;  // 524288 threads, 8 elems each
  const float4* src = (const float4*)feats + (size_t)tid * 2;
  float4 a = src[0];
  float4 b = src[1];
  bf16x8 o;
  o[0] = (short)f2bf(a.x); o[1] = (short)f2bf(a.y);
  o[2] = (short)f2bf(a.z); o[3] = (short)f2bf(a.w);
  o[4] = (short)f2bf(b.x); o[5] = (short)f2bf(b.y);
  o[6] = (short)f2bf(b.z); o[7] = (short)f2bf(b.w);
  *(bf16x8*)(fb + (size_t)tid * 8) = o;
  if (tid < NN) atomicAdd(&cnt[labels[tid]], 1);
}

// Kernel 2: fused sim = F F^T tile GEMM + exp/mask row-partial accumulation.
// Block: 512 threads = 8 waves; wave w owns rows rowTile*128 + w*16 .. +15.
// Iterates 1024 columns (its col chunk) in tiles of 64, staged in LDS.
__global__ __launch_bounds__(512) void
scl_main_kernel(const unsigned short* __restrict__ fb,
                const int* __restrict__ labels,
                float* __restrict__ Sarr, float* __restrict__ Parr) {
  __shared__ unsigned short lds[BN * KK];  // 64 KB, [col][k], k-chunks XOR-swizzled

  const int bid = blockIdx.x;
  const int rowTile = bid / CSPLIT;   // 0..63
  const int colChunk = bid % CSPLIT;  // 0..7  (== XCD id for default dispatch)
  const int tid = threadIdx.x;
  const int w = tid >> 6;
  const int l = tid & 63;
  const int lo = l & 15;  // A-row / B-col / C-col lane index
  const int g = l >> 4;   // k-group (operands) / row-group (C)

  const int row0 = rowTile * BM + w * 16;
  const int myrow = row0 + g * 4;  // this lane accumulates rows myrow..myrow+3

  // A fragments in registers: row = row0+lo, k = ks*32 + g*8 .. +7
  bf16x8 Af[16];
  const unsigned short* arow = fb + (size_t)(row0 + lo) * KK;
#pragma unroll
  for (int ks = 0; ks < 16; ++ks)
    Af[ks] = *(const bf16x8*)(arow + ks * 32 + g * 8);

  int labr[4];
#pragma unroll
  for (int r = 0; r < 4; ++r) labr[r] = labels[myrow + r];

  f32x4 Sacc = {0.f, 0.f, 0.f, 0.f};
  f32x4 Pacc = {0.f, 0.f, 0.f, 0.f};

  const int colbase0 = colChunk * COLS_PER_BLOCK;

  for (int t = 0; t < NTILES; ++t) {
    const int colbase = colbase0 + t * BN;
    __syncthreads();  // previous tile fully consumed before overwrite
    // Stage: wave w stages cols w*8 .. w*8+7 (one 1KB global_load_lds each).
    // LDS dest is linear (lane*16); global source is inverse-XOR-swizzled so a
    // swizzled ds_read is bank-conflict-free (stride-1024B tile otherwise 32-way).
#pragma unroll
    for (int j = 0; j < 8; ++j) {
      const int col = w * 8 + j;  // wave-uniform
      const int kc = (l & 56) | ((l ^ col) & 7);
      const unsigned short* src = fb + (size_t)(colbase + col) * KK + kc * 8;
      load_lds16((const void*)src, (void*)&lds[col * KK]);
    }
    __syncthreads();  // compiler emits vmcnt(0) drain before barrier

#pragma unroll
    for (int st = 0; st < 4; ++st) {
      const int ct = st * 16 + lo;        // col within tile
      const int colg = colbase + ct;      // global col
      const int labc = labels[colg];
      f32x4 acc = {0.f, 0.f, 0.f, 0.f};
#pragma unroll
      for (int ks = 0; ks < 16; ++ks) {
        const int kc = ks * 4 + g;
        const int phys = (kc & 56) | ((kc ^ ct) & 7);
        bf16x8 Bf = *(const bf16x8*)(&lds[ct * KK + phys * 8]);
        acc = __builtin_amdgcn_mfma_f32_16x16x32_bf16(Af[ks], Bf, acc, 0, 0, 0);
      }
#pragma unroll
      for (int r = 0; r < 4; ++r) {
        const float sim = acc[r];
        const int row = myrow + r;
        const float logit = sim * INVT;
        const float e = __expf(logit - INVT);  // exp(logits - M), M = 1/T
        const bool self = (colg == row);
        if (!self) {
          Sacc[r] += e;
          if (labc == labr[r]) Pacc[r] += logit;
        }
      }
    }
  }

  // Row-sum reduce across the 16 lanes sharing a row set (xor 1,2,4,8), then
  // one atomicAdd per row per block.
#pragma unroll
  for (int r = 0; r < 4; ++r) {
    float s = Sacc[r], p = Pacc[r];
#pragma unroll
    for (int m = 1; m < 16; m <<= 1) {
      s += __shfl_xor(s, m, 64);
      p += __shfl_xor(p, m, 64);
    }
    if (lo == 0) {
      atomicAdd(&Sarr[myrow + r], s);
      atomicAdd(&Parr[myrow + r], p);
    }
  }
}

// Kernel 3: per-row loss terms + mean reduction into scalar.
__global__ void finish_kernel(const float* __restrict__ Sarr,
                              const float* __restrict__ Parr,
                              const int* __restrict__ labels,
                              const int* __restrict__ cnt,
                              float* __restrict__ out) {
  int i = blockIdx.x * 256 + threadIdx.x;
  float v = 0.f;
  if (i < NN) {
    float C = (float)(cnt[labels[i]] - 1);
    float lp = Parr[i] - C * (INVT + logf(Sarr[i] + EPSF));
    v = lp / (C + EPSF);
  }
#pragma unroll
  for (int m = 1; m < 64; m <<= 1) v += __shfl_xor(v, m, 64);
  if ((threadIdx.x & 63) == 0) atomicAdd(out, -v * (1.0f / NN));
}

extern "C" void kernel_launch(void* const* d_in, const int* in_sizes, int n_in,
                              void* d_out, int out_size, void* d_ws, size_t ws_size,
                              hipStream_t stream) {
  const float* feats = (const float*)d_in[0];
  const int* labels = (const int*)d_in[1];

  // ws layout: [0, 8MB) bf16 feats; then S (8192 f32), P (8192 f32), cnt (128 i32)
  unsigned short* fb = (unsigned short*)d_ws;
  const size_t FB_BYTES = (size_t)NN * KK * 2;  // 8388608
  float* Sarr = (float*)((char*)d_ws + FB_BYTES);
  float* Parr = Sarr + NN;
  int* cnt = (int*)(Parr + NN);

  hipMemsetAsync((char*)d_ws + FB_BYTES, 0, (size_t)NN * 8 + 512, stream);
  hipMemsetAsync(d_out, 0, sizeof(float), stream);

  prep_kernel<<<dim3((NN * KK / 8) / 256), dim3(256), 0, stream>>>(feats, labels, fb, cnt);
  scl_main_kernel<<<dim3(64 * CSPLIT), dim3(512), 0, stream>>>(fb, labels, Sarr, Parr);
  finish_kernel<<<dim3(NN / 256), dim3(256), 0, stream>>>(Sarr, Parr, labels, cnt, (float*)d_out);
}

// Round 3
// 99.338 us; speedup vs baseline: 1.5319x; 1.5319x over previous
//
#include <hip/hip_runtime.h>

#define NN 8192
#define KK 512
#define INVT 14.285714285714286f   /* 1/0.07 */
#define K2E 20.60992915555662f     /* (1/0.07) * log2(e) */
#define EPSF 1e-6f

#define BM 128
#define BN 64
#define CSPLIT 8
#define COLS_PER_BLOCK (NN / CSPLIT) /* 1024 */
#define NTILES (COLS_PER_BLOCK / BN) /* 16 */

typedef short bf16x8 __attribute__((ext_vector_type(8)));
typedef float f32x4 __attribute__((ext_vector_type(4)));

__device__ __forceinline__ unsigned short f2bf(float f) {
  unsigned int u = __float_as_uint(f);
  u = u + 0x7FFFu + ((u >> 16) & 1u);
  return (unsigned short)(u >> 16);
}

__device__ __forceinline__ void load_lds16(const void* g, void* l) {
  __builtin_amdgcn_global_load_lds(
      (const __attribute__((address_space(1))) unsigned int*)g,
      (__attribute__((address_space(3))) unsigned int*)l, 16, 0, 0);
}

// Kernel 1: fp32 -> bf16 conversion of features + per-class counts.
__global__ void prep_kernel(const float* __restrict__ feats,
                            const int* __restrict__ labels,
                            unsigned short* __restrict__ fb,
                            int* __restrict__ cnt) {
  int tid = blockIdx.x * 256 + threadIdx.x;  // 524288 threads, 8 elems each
  const float4* src = (const float4*)feats + (size_t)tid * 2;
  float4 a = src[0];
  float4 b = src[1];
  bf16x8 o;
  o[0] = (short)f2bf(a.x); o[1] = (short)f2bf(a.y);
  o[2] = (short)f2bf(a.z); o[3] = (short)f2bf(a.w);
  o[4] = (short)f2bf(b.x); o[5] = (short)f2bf(b.y);
  o[6] = (short)f2bf(b.z); o[7] = (short)f2bf(b.w);
  *(bf16x8*)(fb + (size_t)tid * 8) = o;
  if (tid < NN) atomicAdd(&cnt[labels[tid]], 1);
}

// Kernel 2: fused sim = F F^T tile GEMM + exp/mask row-partial accumulation.
// Block: 256 threads = 4 waves; wave w owns 32 rows (2 MFMA row-fragments),
// so each 1KB B ds_read feeds 2 MFMAs (halved LDS traffic per FLOP).
__global__ __launch_bounds__(256, 2) void
scl_main_kernel(const unsigned short* __restrict__ fb,
                const int* __restrict__ labels,
                float* __restrict__ Sarr, float* __restrict__ Parr) {
  __shared__ unsigned short lds[BN * KK];  // 64 KB, [col][k], k-chunks XOR-swizzled

  const int bid = blockIdx.x;
  const int rowTile = bid / CSPLIT;   // 0..63
  const int colChunk = bid % CSPLIT;  // 0..7  (== XCD id for default dispatch)
  const bool diagBlk = ((rowTile >> 3) == colChunk);  // block range hits diagonal
  const int tid = threadIdx.x;
  const int w = tid >> 6;
  const int l = tid & 63;
  const int lo = l & 15;  // A-row / B-col / C-col lane index
  const int g = l >> 4;   // k-group (operands) / row-group (C)

  const int row0 = rowTile * BM + w * 32;
  const int myrow0 = row0 + g * 4;        // frag0 C rows myrow0..+3
  const int myrow1 = row0 + 16 + g * 4;   // frag1 C rows

  // A fragments in registers: frag f row = row0 + f*16 + lo, k = ks*32 + g*8 ..+7
  bf16x8 Af0[16], Af1[16];
  {
    const unsigned short* a0 = fb + (size_t)(row0 + lo) * KK;
    const unsigned short* a1 = fb + (size_t)(row0 + 16 + lo) * KK;
#pragma unroll
    for (int ks = 0; ks < 16; ++ks) {
      Af0[ks] = *(const bf16x8*)(a0 + ks * 32 + g * 8);
      Af1[ks] = *(const bf16x8*)(a1 + ks * 32 + g * 8);
    }
  }

  int labr0[4], labr1[4];
#pragma unroll
  for (int r = 0; r < 4; ++r) {
    labr0[r] = labels[myrow0 + r];
    labr1[r] = labels[myrow1 + r];
  }

  f32x4 Sac0 = {0.f,0.f,0.f,0.f}, Sac1 = {0.f,0.f,0.f,0.f};
  f32x4 Pac0 = {0.f,0.f,0.f,0.f}, Pac1 = {0.f,0.f,0.f,0.f};

  const int colbase0 = colChunk * COLS_PER_BLOCK;

  for (int t = 0; t < NTILES; ++t) {
    const int colbase = colbase0 + t * BN;
    __syncthreads();  // previous tile fully consumed before overwrite
    // Stage 64 cols x 1KB; wave w stages cols w*16..w*16+15.
    // LDS dest linear (lane*16); global source inverse-XOR-swizzled so the
    // swizzled ds_read spreads the stride-1024B tile across banks.
#pragma unroll
    for (int j = 0; j < 16; ++j) {
      const int col = w * 16 + j;  // wave-uniform
      const int kc = (l & 56) | ((l ^ col) & 7);
      const unsigned short* src = fb + (size_t)(colbase + col) * KK + kc * 8;
      load_lds16((const void*)src, (void*)&lds[col * KK]);
    }
    __syncthreads();

#pragma unroll
    for (int st = 0; st < 4; ++st) {
      const int ct = st * 16 + lo;        // col within tile
      const int colg = colbase + ct;      // global col
      const int labc = labels[colg];
      f32x4 a0 = {0.f,0.f,0.f,0.f};
      f32x4 a1 = {0.f,0.f,0.f,0.f};
#pragma unroll
      for (int ks = 0; ks < 16; ++ks) {
        const int kc = ks * 4 + g;
        const int phys = (kc & 56) | ((kc ^ ct) & 7);
        bf16x8 Bf = *(const bf16x8*)(&lds[ct * KK + phys * 8]);
        a0 = __builtin_amdgcn_mfma_f32_16x16x32_bf16(Af0[ks], Bf, a0, 0, 0, 0);
        a1 = __builtin_amdgcn_mfma_f32_16x16x32_bf16(Af1[ks], Bf, a1, 0, 0, 0);
      }
#pragma unroll
      for (int r = 0; r < 4; ++r) {
        const float s0 = a0[r];
        const float e0 = __builtin_amdgcn_exp2f(__builtin_fmaf(s0, K2E, -K2E));
        Sac0[r] += e0;
        if (labc == labr0[r]) Pac0[r] += s0;
        const float s1 = a1[r];
        const float e1 = __builtin_amdgcn_exp2f(__builtin_fmaf(s1, K2E, -K2E));
        Sac1[r] += e1;
        if (labc == labr1[r]) Pac1[r] += s1;
        if (diagBlk) {  // subtract the self term (added above; self always label-matches)
          if (colg == myrow0 + r) { Sac0[r] -= e0; Pac0[r] -= s0; }
          if (colg == myrow1 + r) { Sac1[r] -= e1; Pac1[r] -= s1; }
        }
      }
    }
  }

  // Row-sum reduce across the 16 lanes sharing a row set, one atomic per row.
#pragma unroll
  for (int r = 0; r < 4; ++r) {
    float s0 = Sac0[r], p0 = Pac0[r], s1 = Sac1[r], p1 = Pac1[r];
#pragma unroll
    for (int m = 1; m < 16; m <<= 1) {
      s0 += __shfl_xor(s0, m, 64);
      p0 += __shfl_xor(p0, m, 64);
      s1 += __shfl_xor(s1, m, 64);
      p1 += __shfl_xor(p1, m, 64);
    }
    if (lo == 0) {
      atomicAdd(&Sarr[myrow0 + r], s0);
      atomicAdd(&Parr[myrow0 + r], p0);
      atomicAdd(&Sarr[myrow1 + r], s1);
      atomicAdd(&Parr[myrow1 + r], p1);
    }
  }
}

// Kernel 3: per-row loss terms + mean reduction into scalar.
// Parr holds raw sum of sims over positives; scale by 1/T here.
__global__ void finish_kernel(const float* __restrict__ Sarr,
                              const float* __restrict__ Parr,
                              const int* __restrict__ labels,
                              const int* __restrict__ cnt,
                              float* __restrict__ out) {
  int i = blockIdx.x * 256 + threadIdx.x;
  float v = 0.f;
  if (i < NN) {
    float C = (float)(cnt[labels[i]] - 1);
    float lp = Parr[i] * INVT - C * (INVT + logf(Sarr[i] + EPSF));
    v = lp / (C + EPSF);
  }
#pragma unroll
  for (int m = 1; m < 64; m <<= 1) v += __shfl_xor(v, m, 64);
  if ((threadIdx.x & 63) == 0) atomicAdd(out, -v * (1.0f / NN));
}

extern "C" void kernel_launch(void* const* d_in, const int* in_sizes, int n_in,
                              void* d_out, int out_size, void* d_ws, size_t ws_size,
                              hipStream_t stream) {
  const float* feats = (const float*)d_in[0];
  const int* labels = (const int*)d_in[1];

  // ws layout: [0, 8MB) bf16 feats; then S (8192 f32), P (8192 f32), cnt (128 i32)
  unsigned short* fb = (unsigned short*)d_ws;
  const size_t FB_BYTES = (size_t)NN * KK * 2;  // 8388608
  float* Sarr = (float*)((char*)d_ws + FB_BYTES);
  float* Parr = Sarr + NN;
  int* cnt = (int*)(Parr + NN);

  hipMemsetAsync((char*)d_ws + FB_BYTES, 0, (size_t)NN * 8 + 512, stream);
  hipMemsetAsync(d_out, 0, sizeof(float), stream);

  prep_kernel<<<dim3((NN * KK / 8) / 256), dim3(256), 0, stream>>>(feats, labels, fb, cnt);
  scl_main_kernel<<<dim3(64 * CSPLIT), dim3(256), 0, stream>>>(fb, labels, Sarr, Parr);
  finish_kernel<<<dim3(NN / 256), dim3(256), 0, stream>>>(Sarr, Parr, labels, cnt, (float*)d_out);
}